// Round 18
// baseline (118.980 us; speedup 1.0000x reference)
//
#include <hip/hip_runtime.h>

#define NN 100000
#define EE 1000000
#define NR 256          // fine dst-ranges
#define RSZ 391         // ceil(NN / NR); NR*RSZ = 100096 >= NN
#define CAP2 8192       // segment capacity per range (mean 3910, sigma ~62)

typedef unsigned short ushort_t;
typedef short bf16x8 __attribute__((ext_vector_type(8)));
typedef float f32x4 __attribute__((ext_vector_type(4)));
typedef int   i32x4 __attribute__((ext_vector_type(4)));   // native vec for NT loads

// ---- bf16 helpers (RTNE pack, shift unpack) -------------------------------
__device__ __forceinline__ unsigned short f2bf(float f) {
    unsigned u = __builtin_bit_cast(unsigned, f);
    u += 0x7fffu + ((u >> 16) & 1u);
    return (unsigned short)(u >> 16);
}
__device__ __forceinline__ float bflo(unsigned u) {
    return __builtin_bit_cast(float, u << 16);
}
__device__ __forceinline__ float bfhi(unsigned u) {
    return __builtin_bit_cast(float, u & 0xffff0000u);
}
__device__ __forceinline__ unsigned pk2(float a, float b) {
    return (unsigned)f2bf(a) | ((unsigned)f2bf(b) << 16);
}

// ---------------------------------------------------------------------------
// K0: cast x (f32) -> xb (bf16).  8 elems/thread.  Block 0 zeroes seg_cnt.
// ---------------------------------------------------------------------------
__global__ __launch_bounds__(256) void k_cast(
    const float* __restrict__ x, ushort_t* __restrict__ xb,
    int* __restrict__ seg_cnt)
{
    if (blockIdx.x == 0) seg_cnt[threadIdx.x] = 0;   // NR == 256 == blockDim
    size_t t = (size_t)blockIdx.x * 256 + threadIdx.x;
    const float4 v0 = *reinterpret_cast<const float4*>(x + t * 8);
    const float4 v1 = *reinterpret_cast<const float4*>(x + t * 8 + 4);
    uint4 r;
    r.x = pk2(v0.x, v0.y); r.y = pk2(v0.z, v0.w);
    r.z = pk2(v1.x, v1.y); r.w = pk2(v1.z, v1.w);
    *reinterpret_cast<uint4*>(xb + t * 8) = r;
}

// ---------------------------------------------------------------------------
// K1: partition edges into 256 fixed-capacity fine-range segments of seg[].
// Entries packed: (loc<<17)|src, loc = dst - r*RSZ.  4096 edges/block,
// LDS-binned, ONE global atomic per range per block.
// ---------------------------------------------------------------------------
__global__ __launch_bounds__(256) void k_part(
    const int* __restrict__ ei, int* __restrict__ seg_cnt, int* __restrict__ seg)
{
    __shared__ int cnt[NR];
    __shared__ int basech[NR];
    const int t  = threadIdx.x;
    const int e0 = (blockIdx.x * 256 + t) * 16;
    cnt[t] = 0;
    __syncthreads();

    int d[16], s[16];
    int nval = 0;
    if (e0 + 15 < EE) {
        #pragma unroll
        for (int q = 0; q < 4; ++q) {
            const i32x4 dv = __builtin_nontemporal_load(
                reinterpret_cast<const i32x4*>(ei + EE + e0 + q * 4));
            const i32x4 sv = __builtin_nontemporal_load(
                reinterpret_cast<const i32x4*>(ei + e0 + q * 4));
            d[q*4+0]=dv.x; d[q*4+1]=dv.y; d[q*4+2]=dv.z; d[q*4+3]=dv.w;
            s[q*4+0]=sv.x; s[q*4+1]=sv.y; s[q*4+2]=sv.z; s[q*4+3]=sv.w;
        }
        nval = 16;
    } else {
        for (int j = 0; j < 16 && e0 + j < EE; ++j) {
            d[j] = ei[EE + e0 + j]; s[j] = ei[e0 + j]; ++nval;
        }
    }
    int rr[16];
    for (int j = 0; j < nval; ++j) {
        rr[j] = d[j] / RSZ;
        atomicAdd(&cnt[rr[j]], 1);
    }
    __syncthreads();
    basech[t] = t * CAP2 + atomicAdd(seg_cnt + t, cnt[t]);
    cnt[t] = 0;
    __syncthreads();
    for (int j = 0; j < nval; ++j) {
        const int r = rr[j];
        const int o = atomicAdd(&cnt[r], 1);
        const int addr = basech[r] + o;
        if (addr < (r + 1) * CAP2)           // 68-sigma overflow guard
            seg[addr] = ((d[j] - r * RSZ) << 17) | s[j];
    }
}

// ---------------------------------------------------------------------------
// K2: per-range {seg_cnt scan + histogram + node scan + LDS counting sort}.
// ONE block per fine range (<=391 nodes, ~3.9K edges).
// ---------------------------------------------------------------------------
__global__ __launch_bounds__(256) void k_sortB(
    const int* __restrict__ seg, const int* __restrict__ seg_cnt,
    int* __restrict__ rowptr, int* __restrict__ srcs)
{
    const int r     = blockIdx.x;
    const int n0    = r * RSZ;
    const int n1    = min(n0 + RSZ, NN);
    const int nrg   = n1 - n0;
    const int sbase = r * CAP2;
    const int t     = threadIdx.x;

    __shared__ int cur[RSZ + 1];
    __shared__ int part[NR];      // reused: seg_cnt scan, then node scan
    __shared__ int lsr[CAP2];

    // inline exclusive scan of seg_cnt -> obase (uniform), total
    const int vc = min(seg_cnt[t], CAP2);
    part[t] = vc;
    __syncthreads();
    for (int off = 1; off < NR; off <<= 1) {
        int u = (t >= off) ? part[t - off] : 0;
        __syncthreads();
        part[t] += u;
        __syncthreads();
    }
    const int m     = min(seg_cnt[r], CAP2);
    const int obase = part[r] - m;
    if (r == NR - 1 && t == NR - 1) rowptr[NN] = part[t];
    __syncthreads();

    for (int i = t; i < nrg; i += 256) cur[i] = 0;
    __syncthreads();
    // pass 1: degree histogram
    for (int i = t; i < m; i += 256)
        atomicAdd(&cur[seg[sbase + i] >> 17], 1);
    __syncthreads();
    // exclusive scan over nrg counters (2 elements/thread)
    const int i0 = 2 * t, i1 = 2 * t + 1;
    const int e0 = (i0 < nrg) ? cur[i0] : 0;
    const int e1 = (i1 < nrg) ? cur[i1] : 0;
    const int s  = e0 + e1;
    part[t] = s;
    __syncthreads();
    for (int off = 1; off < 256; off <<= 1) {
        int u = (t >= off) ? part[t - off] : 0;
        __syncthreads();
        part[t] += u;
        __syncthreads();
    }
    const int ex = part[t] - s;
    __syncthreads();
    if (i0 < nrg) { rowptr[n0 + i0] = obase + ex;      cur[i0] = ex; }
    if (i1 < nrg) { rowptr[n0 + i1] = obase + ex + e0; cur[i1] = ex + e0; }
    __syncthreads();
    // pass 2: LDS counting scatter
    for (int i = t; i < m; i += 256) {
        const int q = seg[sbase + i];
        const int pos = atomicAdd(&cur[q >> 17], 1);
        if (pos < CAP2) lsr[pos] = q & 0x1FFFF;
    }
    __syncthreads();
    // sequential coalesced writeback
    for (int i = t; i < m; i += 256)
        srcs[obase + i] = lsr[i];
}

// ---------------------------------------------------------------------------
// K3: gather-mean over bf16 stride-64 rows (128B/row).  8 lanes/node x 16B,
// 8 nodes/wave, full batches issue 8 row-loads back-to-back (deep MLP).
// ---------------------------------------------------------------------------
__global__ __launch_bounds__(256, 8) void k_gather1(
    const ushort_t* __restrict__ rows, const int* __restrict__ rowptr,
    const int* __restrict__ srcs, ushort_t* __restrict__ aggm)
{
    const int lane = threadIdx.x & 63;
    const int w    = threadIdx.x >> 6;
    const int p    = lane & 7;
    const int gb   = lane & 56;
    const int node = blockIdx.x * 32 + w * 8 + (lane >> 3);

    const int beg = rowptr[node];
    const int nb  = rowptr[node + 1] - beg;

    float a0=0,a1=0,a2=0,a3=0,a4=0,a5=0,a6=0,a7=0;
    for (int j0 = 0; j0 < nb; j0 += 8) {
        const int cnt = min(nb - j0, 8);
        const int idx = (p < cnt) ? __builtin_nontemporal_load(srcs + beg + j0 + p) : 0;
        if (cnt == 8) {
            // 8 loads in flight before any accumulation
            uint4 v[8];
            #pragma unroll
            for (int q = 0; q < 8; ++q) {
                const int sq = __shfl(idx, gb + q);
                v[q] = *reinterpret_cast<const uint4*>(rows + (size_t)sq * 64 + p * 8);
            }
            #pragma unroll
            for (int q = 0; q < 8; ++q) {
                a0 += bflo(v[q].x); a1 += bfhi(v[q].x);
                a2 += bflo(v[q].y); a3 += bfhi(v[q].y);
                a4 += bflo(v[q].z); a5 += bfhi(v[q].z);
                a6 += bflo(v[q].w); a7 += bfhi(v[q].w);
            }
        } else {
            for (int t = 0; t < cnt; ++t) {
                const int s = __shfl(idx, gb + t);
                const uint4 vv = *reinterpret_cast<const uint4*>(rows + (size_t)s * 64 + p * 8);
                a0 += bflo(vv.x); a1 += bfhi(vv.x); a2 += bflo(vv.y); a3 += bfhi(vv.y);
                a4 += bflo(vv.z); a5 += bfhi(vv.z); a6 += bflo(vv.w); a7 += bfhi(vv.w);
            }
        }
    }
    const float inv = 1.0f / (float)max(nb, 1);
    uint4 r;
    r.x = pk2(a0*inv, a1*inv); r.y = pk2(a2*inv, a3*inv);
    r.z = pk2(a4*inv, a5*inv); r.w = pk2(a6*inv, a7*inv);
    *reinterpret_cast<uint4*>(aggm + (size_t)node * 64 + p * 8) = r;
}

// ---------------------------------------------------------------------------
// K4: MFMA dense layer.  256 thr = 4 waves; wave owns 64 nodes (4 tiles).
// ---------------------------------------------------------------------------
__global__ __launch_bounds__(256) void k_dense1(
    const ushort_t* __restrict__ xb, const ushort_t* __restrict__ aggm_b,
    const float* __restrict__ W1l, const float* __restrict__ W1r,
    const float* __restrict__ b1,  const float* __restrict__ W2l,
    const float* __restrict__ W2r, const float* __restrict__ b2,
    ushort_t* __restrict__ hW2b, float* __restrict__ base)
{
    __shared__ __align__(16) ushort_t sW1T[64 * 136];
    __shared__ __align__(16) ushort_t sW2T[80 * 72];
    __shared__ __align__(16) ushort_t sH[4][16 * 72];
    __shared__ float sB1[64];
    __shared__ float sB2[40];

    const int t = threadIdx.x;
    {
        const int n = t & 63, kr = t >> 6;
        for (int i = 0; i < 32; ++i) {
            int k = kr * 32 + i;
            float v = (k < 64) ? W1l[k * 64 + n] : W1r[(k - 64) * 64 + n];
            sW1T[n * 136 + k] = f2bf(v);
        }
    }
    for (int idx = t; idx < 80 * 64; idx += 256) {
        int n2 = idx % 80, k = idx / 80;
        float v = (n2 < 40) ? W2l[k * 40 + n2] : W2r[k * 40 + (n2 - 40)];
        sW2T[n2 * 72 + k] = f2bf(v);
    }
    if (t < 64) sB1[t] = b1[t];
    if (t < 40) sB2[t] = b2[t];
    __syncthreads();

    const int w = t >> 6, lane = t & 63;
    const int l15 = lane & 15, g = lane >> 4;
    const f32x4 zero = {0.f, 0.f, 0.f, 0.f};

    for (int it = 0; it < 4; ++it) {
        const int nbase = blockIdx.x * 256 + w * 64 + it * 16;
        const int arow  = min(nbase + l15, NN - 1);

        f32x4 acc0 = zero, acc1 = zero, acc2_ = zero, acc3 = zero;
        bf16x8 afr[4];
        #pragma unroll
        for (int ks = 0; ks < 4; ++ks) {
            const int k0 = ks * 32;
            const ushort_t* src = (k0 < 64)
                ? (aggm_b + (size_t)arow * 64 + k0 + 8 * g)
                : (xb     + (size_t)arow * 64 + (k0 - 64) + 8 * g);
            afr[ks] = *reinterpret_cast<const bf16x8*>(src);
        }
        #pragma unroll
        for (int ks = 0; ks < 4; ++ks) {
            const bf16x8 b0  = *reinterpret_cast<const bf16x8*>(&sW1T[( 0 + l15) * 136 + ks * 32 + 8 * g]);
            const bf16x8 b1f = *reinterpret_cast<const bf16x8*>(&sW1T[(16 + l15) * 136 + ks * 32 + 8 * g]);
            const bf16x8 b2f = *reinterpret_cast<const bf16x8*>(&sW1T[(32 + l15) * 136 + ks * 32 + 8 * g]);
            const bf16x8 b3f = *reinterpret_cast<const bf16x8*>(&sW1T[(48 + l15) * 136 + ks * 32 + 8 * g]);
            acc0  = __builtin_amdgcn_mfma_f32_16x16x32_bf16(afr[ks], b0,  acc0,  0, 0, 0);
            acc1  = __builtin_amdgcn_mfma_f32_16x16x32_bf16(afr[ks], b1f, acc1,  0, 0, 0);
            acc2_ = __builtin_amdgcn_mfma_f32_16x16x32_bf16(afr[ks], b2f, acc2_, 0, 0, 0);
            acc3  = __builtin_amdgcn_mfma_f32_16x16x32_bf16(afr[ks], b3f, acc3,  0, 0, 0);
        }

        {
            const float bb0 = sB1[ 0 + l15], bb1 = sB1[16 + l15];
            const float bb2 = sB1[32 + l15], bb3 = sB1[48 + l15];
            #pragma unroll
            for (int r = 0; r < 4; ++r) {
                const int row = g * 4 + r;
                sH[w][row * 72 +  0 + l15] = f2bf(fmaxf(acc0[r]  + bb0, 0.f));
                sH[w][row * 72 + 16 + l15] = f2bf(fmaxf(acc1[r]  + bb1, 0.f));
                sH[w][row * 72 + 32 + l15] = f2bf(fmaxf(acc2_[r] + bb2, 0.f));
                sH[w][row * 72 + 48 + l15] = f2bf(fmaxf(acc3[r]  + bb3, 0.f));
            }
        }
        __syncthreads();

        bf16x8 a2[2];
        a2[0] = *reinterpret_cast<const bf16x8*>(&sH[w][l15 * 72 +  0 + 8 * g]);
        a2[1] = *reinterpret_cast<const bf16x8*>(&sH[w][l15 * 72 + 32 + 8 * g]);
        f32x4 o[5] = {zero, zero, zero, zero, zero};
        #pragma unroll
        for (int nt = 0; nt < 5; ++nt) {
            #pragma unroll
            for (int ks = 0; ks < 2; ++ks) {
                const bf16x8 bfr = *reinterpret_cast<const bf16x8*>(
                    &sW2T[(nt * 16 + l15) * 72 + ks * 32 + 8 * g]);
                o[nt] = __builtin_amdgcn_mfma_f32_16x16x32_bf16(a2[ks], bfr, o[nt], 0, 0, 0);
            }
        }
        __syncthreads();

        #pragma unroll
        for (int nt = 0; nt < 5; ++nt) {
            const int f2 = nt * 16 + l15;
            #pragma unroll
            for (int r = 0; r < 4; ++r) {
                const int node = nbase + g * 4 + r;
                if (node < NN) {
                    const float v = o[nt][r];
                    if (f2 < 40)
                        hW2b[(size_t)node * 40 + f2] = f2bf(v);
                    if (f2 >= 40)
                        base[(size_t)node * 40 + (f2 - 40)] = v + sB2[f2 - 40];
                }
            }
        }
    }
}

// ---------------------------------------------------------------------------
// K5: gather-mean over hW2b (bf16 stride-40, 80B rows) + base -> out.
// ---------------------------------------------------------------------------
__global__ __launch_bounds__(256, 8) void k_gather2(
    const ushort_t* __restrict__ rows, const int* __restrict__ rowptr,
    const int* __restrict__ srcs, const float* __restrict__ base,
    float* __restrict__ out)
{
    const int lane = threadIdx.x & 63;
    const int w    = threadIdx.x >> 6;
    const int p    = lane & 7;
    const int gb   = lane & 56;
    const int node = blockIdx.x * 32 + w * 8 + (lane >> 3);

    const int beg = rowptr[node];
    const int nb  = rowptr[node + 1] - beg;

    float a0=0,a1=0,a2=0,a3=0,a4=0,a5=0,a6=0,a7=0;
    for (int j0 = 0; j0 < nb; j0 += 8) {
        const int cnt = min(nb - j0, 8);
        const int idx = (p < cnt) ? __builtin_nontemporal_load(srcs + beg + j0 + p) : 0;
        if (cnt == 8) {
            uint4 v[8];
            #pragma unroll
            for (int q = 0; q < 8; ++q) {
                const int sq = __shfl(idx, gb + q);
                if (p < 5)
                    v[q] = *reinterpret_cast<const uint4*>(rows + (size_t)sq * 40 + p * 8);
            }
            if (p < 5) {
                #pragma unroll
                for (int q = 0; q < 8; ++q) {
                    a0 += bflo(v[q].x); a1 += bfhi(v[q].x);
                    a2 += bflo(v[q].y); a3 += bfhi(v[q].y);
                    a4 += bflo(v[q].z); a5 += bfhi(v[q].z);
                    a6 += bflo(v[q].w); a7 += bfhi(v[q].w);
                }
            }
        } else {
            for (int t = 0; t < cnt; ++t) {
                const int s = __shfl(idx, gb + t);
                if (p < 5) {
                    const uint4 vv = *reinterpret_cast<const uint4*>(rows + (size_t)s * 40 + p * 8);
                    a0 += bflo(vv.x); a1 += bfhi(vv.x); a2 += bflo(vv.y); a3 += bfhi(vv.y);
                    a4 += bflo(vv.z); a5 += bfhi(vv.z); a6 += bflo(vv.w); a7 += bfhi(vv.w);
                }
            }
        }
    }
    if (p < 5) {
        const float inv = 1.0f / (float)max(nb, 1);
        const float4 bb0 = *reinterpret_cast<const float4*>(base + (size_t)node * 40 + p * 8);
        const float4 bb1 = *reinterpret_cast<const float4*>(base + (size_t)node * 40 + p * 8 + 4);
        float4 r0, r1;
        r0.x = a0*inv + bb0.x; r0.y = a1*inv + bb0.y; r0.z = a2*inv + bb0.z; r0.w = a3*inv + bb0.w;
        r1.x = a4*inv + bb1.x; r1.y = a5*inv + bb1.y; r1.z = a6*inv + bb1.z; r1.w = a7*inv + bb1.w;
        *reinterpret_cast<float4*>(out + (size_t)node * 40 + p * 8)     = r0;
        *reinterpret_cast<float4*>(out + (size_t)node * 40 + p * 8 + 4) = r1;
    }
}

// ---------------------------------------------------------------------------
// Workspace (4-byte units unless noted):
//   [0, NR)                  seg_cnt (int)   <- zeroed by k_cast block 0
//   [NR, NR+NN+1+pad)        rowptr (int)
//   [NR+NN+8, +EE)           srcs (int)
//   then seg (int x NR*CAP2 = 8MB packed)
//   bf16: xb (NN*64), aggm_b (NN*64), hW2b (NN*40); f32: base (NN*40)
// ---------------------------------------------------------------------------
extern "C" void kernel_launch(void* const* d_in, const int* in_sizes, int n_in,
                              void* d_out, int out_size, void* d_ws, size_t ws_size,
                              hipStream_t stream) {
    const float* x   = (const float*)d_in[0];
    const int*   ei  = (const int*)  d_in[1];
    const float* W1l = (const float*)d_in[2];
    const float* W1r = (const float*)d_in[3];
    const float* b1  = (const float*)d_in[4];
    const float* W2l = (const float*)d_in[5];
    const float* W2r = (const float*)d_in[6];
    const float* b2  = (const float*)d_in[7];
    float* out = (float*)d_out;

    int* wsi = (int*)d_ws;
    int* seg_cnt = wsi;                            // NR
    int* rowptr  = wsi + NR;                       // NN+1 (+pad)
    int* srcs    = wsi + NR + NN + 8;              // EE
    int* seg     = srcs + EE;                      // NR*CAP2 packed ints
    ushort_t* xb     = (ushort_t*)(seg + (size_t)NR * CAP2);
    ushort_t* aggm_b = xb     + (size_t)NN * 64;
    ushort_t* hW2b   = aggm_b + (size_t)NN * 64;
    float*    base   = (float*)(hW2b + (size_t)NN * 40);

    k_cast<<<NN * 64 / 8 / 256, 256, 0, stream>>>(x, xb, seg_cnt);
    k_part<<<(EE + 4095) / 4096, 256, 0, stream>>>(ei, seg_cnt, seg);
    k_sortB<<<NR, 256, 0, stream>>>(seg, seg_cnt, rowptr, srcs);
    k_gather1<<<NN / 32, 256, 0, stream>>>(xb, rowptr, srcs, aggm_b);
    k_dense1<<<(NN + 255) / 256, 256, 0, stream>>>(xb, aggm_b, W1l, W1r, b1,
                                                   W2l, W2r, b2, hW2b, base);
    k_gather2<<<NN / 32, 256, 0, stream>>>(hW2b, rowptr, srcs, base, out);
}

// Round 19
// 112.565 us; speedup vs baseline: 1.0570x; 1.0570x over previous
//
#include <hip/hip_runtime.h>

#define NN 100000
#define EE 1000000
#define NR 256          // fine dst-ranges
#define RSZ 391         // ceil(NN / NR); NR*RSZ = 100096 >= NN
#define CAP2 8192       // segment capacity per range (mean 3910, sigma ~62)

typedef unsigned short ushort_t;
typedef short bf16x8 __attribute__((ext_vector_type(8)));
typedef float f32x4 __attribute__((ext_vector_type(4)));
typedef int   i32x4 __attribute__((ext_vector_type(4)));   // native vec for NT loads

// ---- bf16 helpers (RTNE pack, shift unpack) -------------------------------
__device__ __forceinline__ unsigned short f2bf(float f) {
    unsigned u = __builtin_bit_cast(unsigned, f);
    u += 0x7fffu + ((u >> 16) & 1u);
    return (unsigned short)(u >> 16);
}
__device__ __forceinline__ float bflo(unsigned u) {
    return __builtin_bit_cast(float, u << 16);
}
__device__ __forceinline__ float bfhi(unsigned u) {
    return __builtin_bit_cast(float, u & 0xffff0000u);
}
__device__ __forceinline__ unsigned pk2(float a, float b) {
    return (unsigned)f2bf(a) | ((unsigned)f2bf(b) << 16);
}

// ---------------------------------------------------------------------------
// K0: cast x (f32) -> xb (bf16).  8 elems/thread.  Block 0 zeroes seg_cnt.
// ---------------------------------------------------------------------------
__global__ __launch_bounds__(256) void k_cast(
    const float* __restrict__ x, ushort_t* __restrict__ xb,
    int* __restrict__ seg_cnt)
{
    if (blockIdx.x == 0) seg_cnt[threadIdx.x] = 0;   // NR == 256 == blockDim
    size_t t = (size_t)blockIdx.x * 256 + threadIdx.x;
    const float4 v0 = *reinterpret_cast<const float4*>(x + t * 8);
    const float4 v1 = *reinterpret_cast<const float4*>(x + t * 8 + 4);
    uint4 r;
    r.x = pk2(v0.x, v0.y); r.y = pk2(v0.z, v0.w);
    r.z = pk2(v1.x, v1.y); r.w = pk2(v1.z, v1.w);
    *reinterpret_cast<uint4*>(xb + t * 8) = r;
}

// ---------------------------------------------------------------------------
// K1: partition edges into 256 fixed-capacity fine-range segments of seg[].
// Entries packed: (loc<<17)|src, loc = dst - r*RSZ.  4096 edges/block,
// LDS-binned, ONE global atomic per range per block.
// ---------------------------------------------------------------------------
__global__ __launch_bounds__(256) void k_part(
    const int* __restrict__ ei, int* __restrict__ seg_cnt, int* __restrict__ seg)
{
    __shared__ int cnt[NR];
    __shared__ int basech[NR];
    const int t  = threadIdx.x;
    const int e0 = (blockIdx.x * 256 + t) * 16;
    cnt[t] = 0;
    __syncthreads();

    int d[16], s[16];
    int nval = 0;
    if (e0 + 15 < EE) {
        #pragma unroll
        for (int q = 0; q < 4; ++q) {
            const i32x4 dv = __builtin_nontemporal_load(
                reinterpret_cast<const i32x4*>(ei + EE + e0 + q * 4));
            const i32x4 sv = __builtin_nontemporal_load(
                reinterpret_cast<const i32x4*>(ei + e0 + q * 4));
            d[q*4+0]=dv.x; d[q*4+1]=dv.y; d[q*4+2]=dv.z; d[q*4+3]=dv.w;
            s[q*4+0]=sv.x; s[q*4+1]=sv.y; s[q*4+2]=sv.z; s[q*4+3]=sv.w;
        }
        nval = 16;
    } else {
        for (int j = 0; j < 16 && e0 + j < EE; ++j) {
            d[j] = ei[EE + e0 + j]; s[j] = ei[e0 + j]; ++nval;
        }
    }
    int rr[16];
    for (int j = 0; j < nval; ++j) {
        rr[j] = d[j] / RSZ;
        atomicAdd(&cnt[rr[j]], 1);
    }
    __syncthreads();
    basech[t] = t * CAP2 + atomicAdd(seg_cnt + t, cnt[t]);
    cnt[t] = 0;
    __syncthreads();
    for (int j = 0; j < nval; ++j) {
        const int r = rr[j];
        const int o = atomicAdd(&cnt[r], 1);
        const int addr = basech[r] + o;
        if (addr < (r + 1) * CAP2)           // 68-sigma overflow guard
            seg[addr] = ((d[j] - r * RSZ) << 17) | s[j];
    }
}

// ---------------------------------------------------------------------------
// K2: per-range {seg_cnt scan + histogram + node scan + LDS counting sort}.
// ONE block per fine range (<=391 nodes, ~3.9K edges).
// ---------------------------------------------------------------------------
__global__ __launch_bounds__(256) void k_sortB(
    const int* __restrict__ seg, const int* __restrict__ seg_cnt,
    int* __restrict__ rowptr, int* __restrict__ srcs)
{
    const int r     = blockIdx.x;
    const int n0    = r * RSZ;
    const int n1    = min(n0 + RSZ, NN);
    const int nrg   = n1 - n0;
    const int sbase = r * CAP2;
    const int t     = threadIdx.x;

    __shared__ int cur[RSZ + 1];
    __shared__ int part[NR];      // reused: seg_cnt scan, then node scan
    __shared__ int lsr[CAP2];

    // inline exclusive scan of seg_cnt -> obase (uniform), total
    const int vc = min(seg_cnt[t], CAP2);
    part[t] = vc;
    __syncthreads();
    for (int off = 1; off < NR; off <<= 1) {
        int u = (t >= off) ? part[t - off] : 0;
        __syncthreads();
        part[t] += u;
        __syncthreads();
    }
    const int m     = min(seg_cnt[r], CAP2);
    const int obase = part[r] - m;
    if (r == NR - 1 && t == NR - 1) rowptr[NN] = part[t];
    __syncthreads();

    for (int i = t; i < nrg; i += 256) cur[i] = 0;
    __syncthreads();
    // pass 1: degree histogram
    for (int i = t; i < m; i += 256)
        atomicAdd(&cur[seg[sbase + i] >> 17], 1);
    __syncthreads();
    // exclusive scan over nrg counters (2 elements/thread)
    const int i0 = 2 * t, i1 = 2 * t + 1;
    const int e0 = (i0 < nrg) ? cur[i0] : 0;
    const int e1 = (i1 < nrg) ? cur[i1] : 0;
    const int s  = e0 + e1;
    part[t] = s;
    __syncthreads();
    for (int off = 1; off < 256; off <<= 1) {
        int u = (t >= off) ? part[t - off] : 0;
        __syncthreads();
        part[t] += u;
        __syncthreads();
    }
    const int ex = part[t] - s;
    __syncthreads();
    if (i0 < nrg) { rowptr[n0 + i0] = obase + ex;      cur[i0] = ex; }
    if (i1 < nrg) { rowptr[n0 + i1] = obase + ex + e0; cur[i1] = ex + e0; }
    __syncthreads();
    // pass 2: LDS counting scatter
    for (int i = t; i < m; i += 256) {
        const int q = seg[sbase + i];
        const int pos = atomicAdd(&cur[q >> 17], 1);
        if (pos < CAP2) lsr[pos] = q & 0x1FFFF;
    }
    __syncthreads();
    // sequential coalesced writeback
    for (int i = t; i < m; i += 256)
        srcs[obase + i] = lsr[i];
}

// ---------------------------------------------------------------------------
// K3: gather-mean over bf16 stride-64 rows (128B/row).  8 lanes/node x 16B,
// 8 nodes/wave, 32 nodes/block, no LDS, 4-way unrolled.  Output bf16 mean.
// ---------------------------------------------------------------------------
__global__ __launch_bounds__(256, 8) void k_gather1(
    const ushort_t* __restrict__ rows, const int* __restrict__ rowptr,
    const int* __restrict__ srcs, ushort_t* __restrict__ aggm)
{
    const int lane = threadIdx.x & 63;
    const int w    = threadIdx.x >> 6;
    const int p    = lane & 7;
    const int gb   = lane & 56;
    const int node = blockIdx.x * 32 + w * 8 + (lane >> 3);

    const int beg = rowptr[node];
    const int nb  = rowptr[node + 1] - beg;

    float a0=0,a1=0,a2=0,a3=0,a4=0,a5=0,a6=0,a7=0;
    for (int j0 = 0; j0 < nb; j0 += 8) {
        const int cnt = min(nb - j0, 8);
        const int idx = (p < cnt) ? __builtin_nontemporal_load(srcs + beg + j0 + p) : 0;
        int t = 0;
        for (; t + 3 < cnt; t += 4) {
            int s0 = __shfl(idx, gb + t),     s1 = __shfl(idx, gb + t + 1);
            int s2 = __shfl(idx, gb + t + 2), s3 = __shfl(idx, gb + t + 3);
            const uint4 v0 = *reinterpret_cast<const uint4*>(rows + (size_t)s0 * 64 + p * 8);
            const uint4 v1 = *reinterpret_cast<const uint4*>(rows + (size_t)s1 * 64 + p * 8);
            const uint4 v2 = *reinterpret_cast<const uint4*>(rows + (size_t)s2 * 64 + p * 8);
            const uint4 v3 = *reinterpret_cast<const uint4*>(rows + (size_t)s3 * 64 + p * 8);
            a0 += bflo(v0.x)+bflo(v1.x)+bflo(v2.x)+bflo(v3.x);
            a1 += bfhi(v0.x)+bfhi(v1.x)+bfhi(v2.x)+bfhi(v3.x);
            a2 += bflo(v0.y)+bflo(v1.y)+bflo(v2.y)+bflo(v3.y);
            a3 += bfhi(v0.y)+bfhi(v1.y)+bfhi(v2.y)+bfhi(v3.y);
            a4 += bflo(v0.z)+bflo(v1.z)+bflo(v2.z)+bflo(v3.z);
            a5 += bfhi(v0.z)+bfhi(v1.z)+bfhi(v2.z)+bfhi(v3.z);
            a6 += bflo(v0.w)+bflo(v1.w)+bflo(v2.w)+bflo(v3.w);
            a7 += bfhi(v0.w)+bfhi(v1.w)+bfhi(v2.w)+bfhi(v3.w);
        }
        for (; t < cnt; ++t) {
            int s = __shfl(idx, gb + t);
            const uint4 v = *reinterpret_cast<const uint4*>(rows + (size_t)s * 64 + p * 8);
            a0 += bflo(v.x); a1 += bfhi(v.x); a2 += bflo(v.y); a3 += bfhi(v.y);
            a4 += bflo(v.z); a5 += bfhi(v.z); a6 += bflo(v.w); a7 += bfhi(v.w);
        }
    }
    const float inv = 1.0f / (float)max(nb, 1);
    uint4 r;
    r.x = pk2(a0*inv, a1*inv); r.y = pk2(a2*inv, a3*inv);
    r.z = pk2(a4*inv, a5*inv); r.w = pk2(a6*inv, a7*inv);
    *reinterpret_cast<uint4*>(aggm + (size_t)node * 64 + p * 8) = r;
}

// ---------------------------------------------------------------------------
// K4: MFMA dense layer.  256 thr = 4 waves; wave owns 64 nodes (4 tiles).
// ---------------------------------------------------------------------------
__global__ __launch_bounds__(256) void k_dense1(
    const ushort_t* __restrict__ xb, const ushort_t* __restrict__ aggm_b,
    const float* __restrict__ W1l, const float* __restrict__ W1r,
    const float* __restrict__ b1,  const float* __restrict__ W2l,
    const float* __restrict__ W2r, const float* __restrict__ b2,
    ushort_t* __restrict__ hW2b, float* __restrict__ base)
{
    __shared__ __align__(16) ushort_t sW1T[64 * 136];
    __shared__ __align__(16) ushort_t sW2T[80 * 72];
    __shared__ __align__(16) ushort_t sH[4][16 * 72];
    __shared__ float sB1[64];
    __shared__ float sB2[40];

    const int t = threadIdx.x;
    {
        const int n = t & 63, kr = t >> 6;
        for (int i = 0; i < 32; ++i) {
            int k = kr * 32 + i;
            float v = (k < 64) ? W1l[k * 64 + n] : W1r[(k - 64) * 64 + n];
            sW1T[n * 136 + k] = f2bf(v);
        }
    }
    for (int idx = t; idx < 80 * 64; idx += 256) {
        int n2 = idx % 80, k = idx / 80;
        float v = (n2 < 40) ? W2l[k * 40 + n2] : W2r[k * 40 + (n2 - 40)];
        sW2T[n2 * 72 + k] = f2bf(v);
    }
    if (t < 64) sB1[t] = b1[t];
    if (t < 40) sB2[t] = b2[t];
    __syncthreads();

    const int w = t >> 6, lane = t & 63;
    const int l15 = lane & 15, g = lane >> 4;
    const f32x4 zero = {0.f, 0.f, 0.f, 0.f};

    for (int it = 0; it < 4; ++it) {
        const int nbase = blockIdx.x * 256 + w * 64 + it * 16;
        const int arow  = min(nbase + l15, NN - 1);

        f32x4 acc0 = zero, acc1 = zero, acc2_ = zero, acc3 = zero;
        bf16x8 afr[4];
        #pragma unroll
        for (int ks = 0; ks < 4; ++ks) {
            const int k0 = ks * 32;
            const ushort_t* src = (k0 < 64)
                ? (aggm_b + (size_t)arow * 64 + k0 + 8 * g)
                : (xb     + (size_t)arow * 64 + (k0 - 64) + 8 * g);
            afr[ks] = *reinterpret_cast<const bf16x8*>(src);
        }
        #pragma unroll
        for (int ks = 0; ks < 4; ++ks) {
            const bf16x8 b0  = *reinterpret_cast<const bf16x8*>(&sW1T[( 0 + l15) * 136 + ks * 32 + 8 * g]);
            const bf16x8 b1f = *reinterpret_cast<const bf16x8*>(&sW1T[(16 + l15) * 136 + ks * 32 + 8 * g]);
            const bf16x8 b2f = *reinterpret_cast<const bf16x8*>(&sW1T[(32 + l15) * 136 + ks * 32 + 8 * g]);
            const bf16x8 b3f = *reinterpret_cast<const bf16x8*>(&sW1T[(48 + l15) * 136 + ks * 32 + 8 * g]);
            acc0  = __builtin_amdgcn_mfma_f32_16x16x32_bf16(afr[ks], b0,  acc0,  0, 0, 0);
            acc1  = __builtin_amdgcn_mfma_f32_16x16x32_bf16(afr[ks], b1f, acc1,  0, 0, 0);
            acc2_ = __builtin_amdgcn_mfma_f32_16x16x32_bf16(afr[ks], b2f, acc2_, 0, 0, 0);
            acc3  = __builtin_amdgcn_mfma_f32_16x16x32_bf16(afr[ks], b3f, acc3,  0, 0, 0);
        }

        {
            const float bb0 = sB1[ 0 + l15], bb1 = sB1[16 + l15];
            const float bb2 = sB1[32 + l15], bb3 = sB1[48 + l15];
            #pragma unroll
            for (int r = 0; r < 4; ++r) {
                const int row = g * 4 + r;
                sH[w][row * 72 +  0 + l15] = f2bf(fmaxf(acc0[r]  + bb0, 0.f));
                sH[w][row * 72 + 16 + l15] = f2bf(fmaxf(acc1[r]  + bb1, 0.f));
                sH[w][row * 72 + 32 + l15] = f2bf(fmaxf(acc2_[r] + bb2, 0.f));
                sH[w][row * 72 + 48 + l15] = f2bf(fmaxf(acc3[r]  + bb3, 0.f));
            }
        }
        __syncthreads();

        bf16x8 a2[2];
        a2[0] = *reinterpret_cast<const bf16x8*>(&sH[w][l15 * 72 +  0 + 8 * g]);
        a2[1] = *reinterpret_cast<const bf16x8*>(&sH[w][l15 * 72 + 32 + 8 * g]);
        f32x4 o[5] = {zero, zero, zero, zero, zero};
        #pragma unroll
        for (int nt = 0; nt < 5; ++nt) {
            #pragma unroll
            for (int ks = 0; ks < 2; ++ks) {
                const bf16x8 bfr = *reinterpret_cast<const bf16x8*>(
                    &sW2T[(nt * 16 + l15) * 72 + ks * 32 + 8 * g]);
                o[nt] = __builtin_amdgcn_mfma_f32_16x16x32_bf16(a2[ks], bfr, o[nt], 0, 0, 0);
            }
        }
        __syncthreads();

        #pragma unroll
        for (int nt = 0; nt < 5; ++nt) {
            const int f2 = nt * 16 + l15;
            #pragma unroll
            for (int r = 0; r < 4; ++r) {
                const int node = nbase + g * 4 + r;
                if (node < NN) {
                    const float v = o[nt][r];
                    if (f2 < 40)
                        hW2b[(size_t)node * 40 + f2] = f2bf(v);
                    if (f2 >= 40)
                        base[(size_t)node * 40 + (f2 - 40)] = v + sB2[f2 - 40];
                }
            }
        }
    }
}

// ---------------------------------------------------------------------------
// K5: gather-mean over hW2b (bf16 stride-40, 80B rows) + base -> out.
// Only lanes p<5 load row data (5 x 16B = 80B); all lanes shfl indices.
// ---------------------------------------------------------------------------
__global__ __launch_bounds__(256, 8) void k_gather2(
    const ushort_t* __restrict__ rows, const int* __restrict__ rowptr,
    const int* __restrict__ srcs, const float* __restrict__ base,
    float* __restrict__ out)
{
    const int lane = threadIdx.x & 63;
    const int w    = threadIdx.x >> 6;
    const int p    = lane & 7;
    const int gb   = lane & 56;
    const int node = blockIdx.x * 32 + w * 8 + (lane >> 3);

    const int beg = rowptr[node];
    const int nb  = rowptr[node + 1] - beg;

    float a0=0,a1=0,a2=0,a3=0,a4=0,a5=0,a6=0,a7=0;
    for (int j0 = 0; j0 < nb; j0 += 8) {
        const int cnt = min(nb - j0, 8);
        const int idx = (p < cnt) ? __builtin_nontemporal_load(srcs + beg + j0 + p) : 0;
        int t = 0;
        for (; t + 3 < cnt; t += 4) {
            int s0 = __shfl(idx, gb + t),     s1 = __shfl(idx, gb + t + 1);
            int s2 = __shfl(idx, gb + t + 2), s3 = __shfl(idx, gb + t + 3);
            if (p < 5) {
                const uint4 v0 = *reinterpret_cast<const uint4*>(rows + (size_t)s0 * 40 + p * 8);
                const uint4 v1 = *reinterpret_cast<const uint4*>(rows + (size_t)s1 * 40 + p * 8);
                const uint4 v2 = *reinterpret_cast<const uint4*>(rows + (size_t)s2 * 40 + p * 8);
                const uint4 v3 = *reinterpret_cast<const uint4*>(rows + (size_t)s3 * 40 + p * 8);
                a0 += bflo(v0.x)+bflo(v1.x)+bflo(v2.x)+bflo(v3.x);
                a1 += bfhi(v0.x)+bfhi(v1.x)+bfhi(v2.x)+bfhi(v3.x);
                a2 += bflo(v0.y)+bflo(v1.y)+bflo(v2.y)+bflo(v3.y);
                a3 += bfhi(v0.y)+bfhi(v1.y)+bfhi(v2.y)+bfhi(v3.y);
                a4 += bflo(v0.z)+bflo(v1.z)+bflo(v2.z)+bflo(v3.z);
                a5 += bfhi(v0.z)+bfhi(v1.z)+bfhi(v2.z)+bfhi(v3.z);
                a6 += bflo(v0.w)+bflo(v1.w)+bflo(v2.w)+bflo(v3.w);
                a7 += bfhi(v0.w)+bfhi(v1.w)+bfhi(v2.w)+bfhi(v3.w);
            }
        }
        for (; t < cnt; ++t) {
            int s = __shfl(idx, gb + t);
            if (p < 5) {
                const uint4 v = *reinterpret_cast<const uint4*>(rows + (size_t)s * 40 + p * 8);
                a0 += bflo(v.x); a1 += bfhi(v.x); a2 += bflo(v.y); a3 += bfhi(v.y);
                a4 += bflo(v.z); a5 += bfhi(v.z); a6 += bflo(v.w); a7 += bfhi(v.w);
            }
        }
    }
    if (p < 5) {
        const float inv = 1.0f / (float)max(nb, 1);
        const float4 bb0 = *reinterpret_cast<const float4*>(base + (size_t)node * 40 + p * 8);
        const float4 bb1 = *reinterpret_cast<const float4*>(base + (size_t)node * 40 + p * 8 + 4);
        float4 r0, r1;
        r0.x = a0*inv + bb0.x; r0.y = a1*inv + bb0.y; r0.z = a2*inv + bb0.z; r0.w = a3*inv + bb0.w;
        r1.x = a4*inv + bb1.x; r1.y = a5*inv + bb1.y; r1.z = a6*inv + bb1.z; r1.w = a7*inv + bb1.w;
        *reinterpret_cast<float4*>(out + (size_t)node * 40 + p * 8)     = r0;
        *reinterpret_cast<float4*>(out + (size_t)node * 40 + p * 8 + 4) = r1;
    }
}

// ---------------------------------------------------------------------------
// Workspace (4-byte units unless noted):
//   [0, NR)                  seg_cnt (int)   <- zeroed by k_cast block 0
//   [NR, NR+NN+1+pad)        rowptr (int)
//   [NR+NN+8, +EE)           srcs (int)
//   then seg (int x NR*CAP2 = 8MB packed)
//   bf16: xb (NN*64), aggm_b (NN*64), hW2b (NN*40); f32: base (NN*40)
// ---------------------------------------------------------------------------
extern "C" void kernel_launch(void* const* d_in, const int* in_sizes, int n_in,
                              void* d_out, int out_size, void* d_ws, size_t ws_size,
                              hipStream_t stream) {
    const float* x   = (const float*)d_in[0];
    const int*   ei  = (const int*)  d_in[1];
    const float* W1l = (const float*)d_in[2];
    const float* W1r = (const float*)d_in[3];
    const float* b1  = (const float*)d_in[4];
    const float* W2l = (const float*)d_in[5];
    const float* W2r = (const float*)d_in[6];
    const float* b2  = (const float*)d_in[7];
    float* out = (float*)d_out;

    int* wsi = (int*)d_ws;
    int* seg_cnt = wsi;                            // NR
    int* rowptr  = wsi + NR;                       // NN+1 (+pad)
    int* srcs    = wsi + NR + NN + 8;              // EE
    int* seg     = srcs + EE;                      // NR*CAP2 packed ints
    ushort_t* xb     = (ushort_t*)(seg + (size_t)NR * CAP2);
    ushort_t* aggm_b = xb     + (size_t)NN * 64;
    ushort_t* hW2b   = aggm_b + (size_t)NN * 64;
    float*    base   = (float*)(hW2b + (size_t)NN * 40);

    k_cast<<<NN * 64 / 8 / 256, 256, 0, stream>>>(x, xb, seg_cnt);
    k_part<<<(EE + 4095) / 4096, 256, 0, stream>>>(ei, seg_cnt, seg);
    k_sortB<<<NR, 256, 0, stream>>>(seg, seg_cnt, rowptr, srcs);
    k_gather1<<<NN / 32, 256, 0, stream>>>(xb, rowptr, srcs, aggm_b);
    k_dense1<<<(NN + 255) / 256, 256, 0, stream>>>(xb, aggm_b, W1l, W1r, b1,
                                                   W2l, W2r, b2, hW2b, base);
    k_gather2<<<NN / 32, 256, 0, stream>>>(hW2b, rowptr, srcs, base, out);
}